// Round 18
// baseline (140.234 us; speedup 1.0000x reference)
//
#include <hip/hip_runtime.h>
#include <math.h>

typedef float v2 __attribute__((ext_vector_type(2)));

#define SCALE 1073741824.0   // 2^30 fixed-point for deterministic atomic sum
#define NPIX 12582912.0      // 16*3*512*512
#define C1f 1e-4f
#define C2f 9e-4f
#define SLOTF 288            // floats per LDS slot: A[0,144) | B[144,288)
#define WAVEF 1376           // 4 slots * 288 + 224 junk floats per wave

struct Wts {
    float w[11];   // V-pass weights
    v2 hp[12];     // H-pass pair weights for element j: (w[j]|0, w[j-1]|0)
};

__device__ __forceinline__ v2 sp(float x) { v2 r; r.x = x; r.y = x; return r; }
__device__ __forceinline__ v2 f2(v2 a, v2 b, v2 c) {
    return __builtin_elementwise_fma(a, b, c);
}

// load one staged row (clamped) into 3-way parity-named f4 buffers (literal P)
#define LOADP(P, grow) do {                                                 \
    int rc_ = (grow); rc_ = rc_ < 0 ? 0 : (rc_ > 511 ? 511 : rc_);          \
    if ((P) == 0)      { r1_0 = *(const float4*)(g1 + rc_ * 512);           \
                         r2_0 = *(const float4*)(g2 + rc_ * 512); }         \
    else if ((P) == 1) { r1_1 = *(const float4*)(g1 + rc_ * 512);           \
                         r2_1 = *(const float4*)(g2 + rc_ * 512); }         \
    else               { r1_2 = *(const float4*)(g1 + rc_ * 512);           \
                         r2_2 = *(const float4*)(g2 + rc_ * 512); }         \
} while (0)

// ds_write buffers P (literal) into LDS slot S (literal), column-masked
#define SWRP(P, S) do {                                                     \
    float4 o1_, o2_;                                                        \
    if ((P) == 0)      { o1_ = r1_0; o2_ = r2_0; }                          \
    else if ((P) == 1) { o1_ = r1_1; o2_ = r2_1; }                          \
    else               { o1_ = r1_2; o2_ = r2_2; }                          \
    o1_.x *= cm1.x; o1_.y *= cm1.y; o1_.z *= cm1.z; o1_.w *= cm1.w;         \
    o2_.x *= cm2.x; o2_.y *= cm2.y; o2_.z *= cm2.z; o2_.w *= cm2.w;         \
    *(float4*)(wr1 + (S) * SLOTF) = o1_;                                    \
    *(float4*)(wr2 + (S) * wr2step) = o2_;                                  \
} while (0)

// One step, phase p literal: ds_read slot p&3, issue load row gr+4 (buf p%3),
// VOUT phase p, HP phase p, ds_write row gr+2 (buf (p+1)%3) to slot (p+2)&3.
#define STEPM(p) do {                                                       \
    const int t_ = 12 * it + (p);                                           \
    const int gr_ = r0 - 5 + t_;                                            \
    v2 a_[7], b_[7];                                                        \
    _Pragma("unroll") for (int k_ = 0; k_ < 7; ++k_) {                      \
        a_[k_] = *(const v2*)(rd + ((p) & 3) * SLOTF + 2 * k_);             \
        b_[k_] = *(const v2*)(rd + ((p) & 3) * SLOTF + 144 + 2 * k_);       \
    }                                                                       \
    LOADP((p) % 3, gr_ + 4);                                                \
    {   /* V-output: ring slots ((p)+1..+11)%12, dead slot = p */           \
        v2 S_ = sp(0.f), D_ = sp(0.f), P_ = sp(0.f), M_ = sp(0.f);          \
        _Pragma("unroll") for (int k_ = 0; k_ < 11; ++k_) {                 \
            const int q_ = ((p) + 1 + k_) % 12;                             \
            const v2 wk_ = sp(W.w[k_]);                                     \
            S_ = f2(wk_, rS[q_], S_); D_ = f2(wk_, rD[q_], D_);             \
            P_ = f2(wk_, rP[q_], P_); M_ = f2(wk_, rM[q_], M_);             \
        }                                                                   \
        const v2 ss_ = S_ * S_, dd_ = D_ * D_;                              \
        const v2 mu12_  = (ss_ - dd_) * sp(0.25f);                          \
        const v2 musq_  = (ss_ + dd_) * sp(0.5f);                           \
        const v2 sig12_ = (P_ - M_) * sp(0.25f) - mu12_;                    \
        const v2 sigsm_ = (P_ + M_) * sp(0.5f) - musq_;                     \
        const v2 num_ = (sp(2.f) * mu12_ + sp(C1f)) *                       \
                        (sp(2.f) * sig12_ + sp(C2f));                       \
        const v2 den_ = (musq_ + sp(C1f)) * (sigsm_ + sp(C2f));             \
        v2 r_;                                                              \
        r_.x = __builtin_amdgcn_rcpf(den_.x);                               \
        r_.y = __builtin_amdgcn_rcpf(den_.y);                               \
        r_ = r_ * (sp(2.f) - den_ * r_);                                    \
        const float vm_ = (t_ >= 11 && (r0 + t_ - 11) < 512) ? 1.f : 0.f;   \
        loc = f2(num_ * sp(vm_), r_, loc);                                  \
    }                                                                       \
    {   /* H-push row gr_ into ring slot p; data pre-masked in LDS */       \
        v2 hS_ = sp(0.f), hD_ = sp(0.f), hP_ = sp(0.f), hM_ = sp(0.f);      \
        _Pragma("unroll") for (int j_ = 0; j_ < 12; ++j_) {                 \
            const int e_ = j_ + 1;          /* element col = c - 6 + e */   \
            const float xa_ = (e_ & 1) ? a_[e_ >> 1].y : a_[e_ >> 1].x;     \
            const float xb_ = (e_ & 1) ? b_[e_ >> 1].y : b_[e_ >> 1].x;     \
            const float u_ = xa_ + xb_, v_ = xa_ - xb_;                     \
            hS_ = f2(W.hp[j_], sp(u_), hS_);                                \
            hD_ = f2(W.hp[j_], sp(v_), hD_);                                \
            hP_ = f2(W.hp[j_], sp(u_ * u_), hP_);                           \
            hM_ = f2(W.hp[j_], sp(v_ * v_), hM_);                           \
        }                                                                   \
        const float m_ = ((unsigned)gr_ < 512u) ? 1.f : 0.f;                \
        const v2 mm_ = sp(m_);                                              \
        rS[(p)] = hS_ * mm_; rD[(p)] = hD_ * mm_;                           \
        rP[(p)] = hP_ * mm_; rM[(p)] = hM_ * mm_;                           \
    }                                                                       \
    SWRP(((p) + 1) % 3, ((p) + 2) & 3);                                     \
    __builtin_amdgcn_sched_barrier(0);                                      \
} while (0)

__global__ __launch_bounds__(256, 3) void ssim_main(
    const float* __restrict__ img1, const float* __restrict__ img2,
    unsigned long long* __restrict__ acc, Wts W)
{
    __shared__ float ldsbuf[4 * WAVEF];        // 22016 B, wave-private areas

    const int tid = threadIdx.x;
    const int lane = tid & 63;
    const int wv = tid >> 6;
    const int r0 = blockIdx.x * 37;            // 14 strips of 37 output rows
    const int plane = blockIdx.y;              // 48 planes
    const int wc = wv * 128;                   // wave's column base
    const int c = wc + 2 * lane;               // thread's columns c, c+1

    const float* baseA = img1 + (size_t)plane * 262144;
    const float* baseB = img2 + (size_t)plane * 262144;
    float* ldsW = ldsbuf + wv * WAVEF;

    // ---- staging roles: 36 f4 chunks/img cover cols [wc-8, wc+136) ------
    // instr1: lanes 0-35 -> img A chunks 0-35; lanes 36-63 -> B chunks 0-27
    const int ch1 = (lane < 36) ? lane : (lane - 36);
    const int cb1 = wc - 8 + 4 * ch1;          // intended (unclamped) col
    const int cc1 = cb1 < 0 ? 0 : (cb1 > 508 ? 508 : cb1);
    const float* g1 = ((lane < 36) ? baseA : baseB) + cc1;
    float* wr1 = ldsW + ((lane < 36) ? 4 * ch1 : 144 + 4 * ch1);
    float4 cm1;
    cm1.x = (cb1 + 0 >= 0 && cb1 + 0 < 512) ? 1.f : 0.f;
    cm1.y = (cb1 + 1 >= 0 && cb1 + 1 < 512) ? 1.f : 0.f;
    cm1.z = (cb1 + 2 >= 0 && cb1 + 2 < 512) ? 1.f : 0.f;
    cm1.w = (cb1 + 3 >= 0 && cb1 + 3 < 512) ? 1.f : 0.f;
    // instr2: lanes 0-7 -> B chunks 28-35; lanes 8-63 -> duplicate line,
    // written to a per-wave junk strip (never read)
    const bool real2 = (lane < 8);
    const int ch2 = real2 ? (28 + lane) : 35;
    const int cb2 = wc - 8 + 4 * ch2;
    const int cc2 = cb2 < 0 ? 0 : (cb2 > 508 ? 508 : cb2);
    const float* g2 = baseB + cc2;
    float* wr2 = ldsW + (real2 ? (144 + 4 * ch2) : (4 * SLOTF + 4 * (lane - 8)));
    const int wr2step = real2 ? SLOTF : 0;
    float4 cm2;
    cm2.x = (real2 && cb2 + 0 >= 0 && cb2 + 0 < 512) ? 1.f : 0.f;
    cm2.y = (real2 && cb2 + 1 >= 0 && cb2 + 1 < 512) ? 1.f : 0.f;
    cm2.z = (real2 && cb2 + 2 >= 0 && cb2 + 2 < 512) ? 1.f : 0.f;
    cm2.w = (real2 && cb2 + 3 >= 0 && cb2 + 3 < 512) ? 1.f : 0.f;

    // window read base: col c-6 sits at slot float 2*lane+2 (A), +144 (B)
    const float* rd = ldsW + 2 * lane + 2;

    v2 rS[12], rD[12], rP[12], rM[12];         // 12-slot register ring
#pragma unroll
    for (int q = 0; q < 12; ++q) {             // zero ring: prologue VOUTs stay
        rS[q] = sp(0.f); rD[q] = sp(0.f);      // finite, vm-masked
        rP[q] = sp(0.f); rM[q] = sp(0.f);
    }
    v2 loc = sp(0.f);
    float4 r1_0, r2_0, r1_1, r2_1, r1_2, r2_2; // 3-way parity stage buffers

    // ---- prologue: slots 0,1 <- rows r0-5,r0-4; preload bufs 1,2 --------
    LOADP(0, r0 - 5);  SWRP(0, 0);
    LOADP(1, r0 - 4);  SWRP(1, 1);
    LOADP(1, r0 - 3);                          // step0 writes this to slot2
    LOADP(2, r0 - 2);                          // step1 writes this to slot3
    __builtin_amdgcn_sched_barrier(0);

    // ---- 48 steps = 4 x 12-step literal body ----------------------------
    for (int it = 0; it < 4; ++it) {
        STEPM(0);  STEPM(1);  STEPM(2);  STEPM(3);
        STEPM(4);  STEPM(5);  STEPM(6);  STEPM(7);
        STEPM(8);  STEPM(9);  STEPM(10); STEPM(11);
    }

    // ---- per-wave reduction -> fixed-point global atomic (no barriers) --
    float l = loc.x + loc.y;
#pragma unroll
    for (int o2 = 32; o2; o2 >>= 1)
        l += __shfl_down(l, o2, 64);
    if (lane == 0) {
        const unsigned long long q =
            (unsigned long long)__double2ll_rn((double)l * SCALE);
        atomicAdd(acc, q);
    }
}

__global__ void ssim_final(const unsigned long long* __restrict__ acc,
                           float* __restrict__ out)
{
    if (threadIdx.x == 0)
        out[0] = (float)((double)(*acc) * (1.0 / SCALE) / NPIX);
}

extern "C" void kernel_launch(void* const* d_in, const int* in_sizes, int n_in,
                              void* d_out, int out_size, void* d_ws, size_t ws_size,
                              hipStream_t stream) {
    const float* img1 = (const float*)d_in[0];
    const float* img2 = (const float*)d_in[1];
    float* out = (float*)d_out;
    unsigned long long* acc = (unsigned long long*)d_ws;

    double g[11], ssum = 0.0;
    for (int i = 0; i < 11; ++i) {
        const double d = (double)(i - 5);
        g[i] = exp(-(d * d) / 4.5);
        ssum += g[i];
    }
    Wts W;
    for (int i = 0; i < 11; ++i) W.w[i] = (float)(g[i] / ssum);
    for (int j = 0; j < 12; ++j) {
        v2 p;
        p.x = (j <= 10) ? W.w[j] : 0.f;      // out0 weight for window col c-5+j
        p.y = (j >= 1) ? W.w[j - 1] : 0.f;   // out1 weight
        W.hp[j] = p;
    }

    hipMemsetAsync(d_ws, 0, sizeof(unsigned long long), stream);
    ssim_main<<<dim3(14, 48), 256, 0, stream>>>(img1, img2, acc, W);
    ssim_final<<<1, 64, 0, stream>>>(acc, out);
}

// Round 19
// 69.814 us; speedup vs baseline: 2.0087x; 2.0087x over previous
//
#include <hip/hip_runtime.h>
#include <math.h>

typedef float v2 __attribute__((ext_vector_type(2)));

#define SCALE 1073741824.0   // 2^30 fixed-point for deterministic atomic sum
#define NPIX 12582912.0      // 16*3*512*512
#define C1f 1e-4f
#define C2f 9e-4f

struct Wts {
    float w[11];   // V-pass weights
    v2 hp[12];     // H-pass pair weights for element j: (w[j]|0, w[j-1]|0)
};

__device__ __forceinline__ v2 sp(float x) { v2 r; r.x = x; r.y = x; return r; }
__device__ __forceinline__ v2 f2(v2 a, v2 b, v2 c) {
    return __builtin_elementwise_fma(a, b, c);
}

__global__ __launch_bounds__(256, 2) void ssim_main(
    const float* __restrict__ img1, const float* __restrict__ img2,
    unsigned long long* __restrict__ acc, Wts W)
{
    __shared__ float red[4];
    const int tid = threadIdx.x;
    const int lane = tid & 63;
    const int wv = tid >> 6;
    const int r0 = blockIdx.x * 33;            // 16 strips of 33 output rows
    const int plane = blockIdx.y;              // 48 planes
    const int c = wv * 128 + 2 * lane;         // this thread's columns c, c+1

    const float* baseA = img1 + (size_t)plane * 262144;
    const float* baseB = img2 + (size_t)plane * 262144;

    // ---- convoy-breaking phase stagger: blocks sharing a SIMD get -------
    // ---- different start phases (hash of blockIdx; 0/384/768/1152 cyc) --
    {
        const unsigned h = (unsigned)(blockIdx.x + 16 * blockIdx.y) * 2654435761u;
        const unsigned ph = h >> 30;           // top 2 bits: 0..3
        if (ph == 1)      __builtin_amdgcn_s_sleep(6);   // ~384 cyc
        else if (ph == 2) __builtin_amdgcn_s_sleep(12);  // ~768 cyc
        else if (ph == 3) __builtin_amdgcn_s_sleep(18);  // ~1152 cyc
    }

    // per-lane clamped chunk offsets (7 x float2 chunks covering [c-6, c+8))
    int off[7];
#pragma unroll
    for (int k = 0; k < 7; ++k) {
        int o = c - 6 + 2 * k;
        off[k] = o < 0 ? 0 : (o > 510 ? 510 : o);
    }
    // per-lane H weight pairs, zeroed where the element column is out of image
    v2 hpl[12];
#pragma unroll
    for (int j = 0; j < 12; ++j) {
        const int col = c - 5 + j;
        hpl[j] = (col >= 0 && col < 512) ? W.hp[j] : sp(0.f);
    }

    v2 rS[11], rD[11], rP[11], rM[11];         // ring: blurred u, v, u^2, v^2
#pragma unroll
    for (int q = 0; q < 11; ++q) {             // zero ring: prologue VOUTs stay
        rS[q] = sp(0.f); rD[q] = sp(0.f);      // finite (den=C1*C2>0), masked
        rP[q] = sp(0.f); rM[q] = sp(0.f);
    }
    v2 a[7], b[7];
    v2 loc = sp(0.f);

    // ---- 44 steps as 4 x one 11-step body (I$-resident, R12 skeleton) ----
    // step t=11*it+p: load source row gr=r0-5+t, VOUT output row r0+t-11
    // (masked vm: t>=11 && row<512), push H-blur of row gr (masked m).
    for (int it = 0; it < 4; ++it) {
        const int t0 = 11 * it;
#pragma unroll
        for (int p = 0; p < 11; ++p) {
            const int t = t0 + p;
            const int gr = r0 - 5 + t;
            const int rc = gr < 0 ? 0 : (gr > 511 ? 511 : gr);
            const float* ra = baseA + rc * 512;
            const float* rb = baseB + rc * 512;
#pragma unroll
            for (int k = 0; k < 7; ++k) {      // issue loads first
                a[k] = *(const v2*)(ra + off[k]);
                b[k] = *(const v2*)(rb + off[k]);
            }
            // V-output (ring-only; overlaps the in-flight loads)
            {
                v2 S = sp(0.f), D = sp(0.f), P = sp(0.f), M = sp(0.f);
#pragma unroll
                for (int k = 0; k < 11; ++k) {
                    const int q = (p + k) % 11; // constant after unroll
                    const v2 wk = sp(W.w[k]);
                    S = f2(wk, rS[q], S);
                    D = f2(wk, rD[q], D);
                    P = f2(wk, rP[q], P);
                    M = f2(wk, rM[q], M);
                }
                const v2 ss = S * S, dd = D * D;
                const v2 mu12  = (ss - dd) * sp(0.25f);
                const v2 musq  = (ss + dd) * sp(0.5f);
                const v2 sig12 = (P - M) * sp(0.25f) - mu12;
                const v2 sigsm = (P + M) * sp(0.5f) - musq;
                const v2 num = (sp(2.f) * mu12 + sp(C1f)) *
                               (sp(2.f) * sig12 + sp(C2f));
                const v2 den = (musq + sp(C1f)) * (sigsm + sp(C2f));
                v2 r;
                r.x = __builtin_amdgcn_rcpf(den.x);
                r.y = __builtin_amdgcn_rcpf(den.y);
                r = r * (sp(2.f) - den * r);   // one NR step
                const float vm =
                    (t >= 11 && (r0 + t - 11) < 512) ? 1.f : 0.f;
                loc = f2(num * sp(vm), r, loc);
            }
            // H-push row gr into ring slot p
            {
                v2 hS = sp(0.f), hD = sp(0.f), hP = sp(0.f), hM = sp(0.f);
#pragma unroll
                for (int j = 0; j < 12; ++j) {
                    const int e = j + 1;       // element col = c - 6 + e
                    const float xa = (e & 1) ? a[e >> 1].y : a[e >> 1].x;
                    const float xb = (e & 1) ? b[e >> 1].y : b[e >> 1].x;
                    const float u = xa + xb, v = xa - xb;
                    hS = f2(hpl[j], sp(u), hS);
                    hD = f2(hpl[j], sp(v), hD);
                    hP = f2(hpl[j], sp(u * u), hP);
                    hM = f2(hpl[j], sp(v * v), hM);
                }
                const float m = ((unsigned)gr < 512u) ? 1.f : 0.f;
                const v2 mm = sp(m);
                rS[p] = hS * mm; rD[p] = hD * mm;
                rP[p] = hP * mm; rM[p] = hM * mm;
            }
            __builtin_amdgcn_sched_barrier(0); // fence: bounds live ranges
        }
    }

    // ---- reduction -> fixed-point global atomic ----
    float l = loc.x + loc.y;
#pragma unroll
    for (int o2 = 32; o2; o2 >>= 1)
        l += __shfl_down(l, o2, 64);
    if (lane == 0) red[wv] = l;
    __syncthreads();
    if (tid == 0) {
        const float bs = red[0] + red[1] + red[2] + red[3];
        const unsigned long long q =
            (unsigned long long)__double2ll_rn((double)bs * SCALE);
        atomicAdd(acc, q);
    }
}

__global__ void ssim_final(const unsigned long long* __restrict__ acc,
                           float* __restrict__ out)
{
    if (threadIdx.x == 0)
        out[0] = (float)((double)(*acc) * (1.0 / SCALE) / NPIX);
}

extern "C" void kernel_launch(void* const* d_in, const int* in_sizes, int n_in,
                              void* d_out, int out_size, void* d_ws, size_t ws_size,
                              hipStream_t stream) {
    const float* img1 = (const float*)d_in[0];
    const float* img2 = (const float*)d_in[1];
    float* out = (float*)d_out;
    unsigned long long* acc = (unsigned long long*)d_ws;

    double g[11], ssum = 0.0;
    for (int i = 0; i < 11; ++i) {
        const double d = (double)(i - 5);
        g[i] = exp(-(d * d) / 4.5);
        ssum += g[i];
    }
    Wts W;
    for (int i = 0; i < 11; ++i) W.w[i] = (float)(g[i] / ssum);
    for (int j = 0; j < 12; ++j) {
        v2 p;
        p.x = (j <= 10) ? W.w[j] : 0.f;      // out0 weight for window col c-5+j
        p.y = (j >= 1) ? W.w[j - 1] : 0.f;   // out1 weight
        W.hp[j] = p;
    }

    hipMemsetAsync(d_ws, 0, sizeof(unsigned long long), stream);
    ssim_main<<<dim3(16, 48), 256, 0, stream>>>(img1, img2, acc, W);
    ssim_final<<<1, 64, 0, stream>>>(acc, out);
}